// Round 1
// baseline (642.942 us; speedup 1.0000x reference)
//
#include <hip/hip_runtime.h>

#define M_TOTAL   2000000
#define NT        512
#define K1_BLOCKS 2048

// -------------------- K1: per-block partial sums of v_src@embs and v_target@embs --------------------
extern "C" __global__ __launch_bounds__(256)
void k_reduce(const float* __restrict__ emb, const float* __restrict__ vsrc,
              const float* __restrict__ vtgt, double* __restrict__ partials)
{
    const int tid = threadIdx.x;
    const int bid = blockIdx.x;
    double acc[32];
#pragma unroll
    for (int i = 0; i < 32; i++) acc[i] = 0.0;

    for (long long r = (long long)bid * 256 + tid; r < M_TOTAL; r += (long long)K1_BLOCKS * 256) {
        const float4* ep = (const float4*)(emb + r * 16);
        float4 e0 = ep[0], e1 = ep[1], e2 = ep[2], e3 = ep[3];
        float ev[16] = { e0.x,e0.y,e0.z,e0.w, e1.x,e1.y,e1.z,e1.w,
                         e2.x,e2.y,e2.z,e2.w, e3.x,e3.y,e3.z,e3.w };
        float n2 = 0.0f;
#pragma unroll
        for (int i = 0; i < 16; i++) n2 = fmaf(ev[i], ev[i], n2);
        float invn = 1.0f / sqrtf(n2);
        float s = vsrc[r];
        float t = vtgt[r];
#pragma unroll
        for (int i = 0; i < 16; i++) {
            float en = ev[i] * invn;
            acc[i]      += (double)s * (double)en;
            acc[16 + i] += (double)t * (double)en;
        }
    }
    // wave reduce (wave = 64)
#pragma unroll
    for (int i = 0; i < 32; i++) {
        double v = acc[i];
#pragma unroll
        for (int off = 32; off; off >>= 1) v += __shfl_down(v, off);
        acc[i] = v;
    }
    __shared__ double lred[4][32];
    int lane = tid & 63, wv = tid >> 6;
    if (lane == 0) {
#pragma unroll
        for (int i = 0; i < 32; i++) lred[wv][i] = acc[i];
    }
    __syncthreads();
    if (tid < 32) {
        double v = lred[0][tid] + lred[1][tid] + lred[2][tid] + lred[3][tid];
        partials[(long long)bid * 32 + tid] = v;
    }
}

// -------------------- K2: the sequential 64-step scan (1 block, 512 threads) --------------------
extern "C" __global__ __launch_bounds__(512)
void k_steps(const double* __restrict__ partials,
             const float* __restrict__ w1g, const float* __restrict__ b1g,
             const float* __restrict__ w2g, const float* __restrict__ b2g,
             const float* __restrict__ w3g, const float* __restrict__ b3g,
             const float* __restrict__ tc,  const float* __restrict__ gum,
             const int* __restrict__ nsp,
             float* __restrict__ outL, float* __restrict__ vf_out)
{
    __shared__ float w1s[32 * 256];
    __shared__ float b1s[256];
    __shared__ float b2s[128];
    __shared__ __align__(16) float h1s[256];
    __shared__ __align__(16) float h2s[128];
    __shared__ float h2p[512];
    __shared__ float xs[32];
    __shared__ float rkeys[8];
    __shared__ int   ridx[8];

    const int t = threadIdx.x;

    // stage-2 reduce of K1 partials -> xs[0:16]=v_cur, xs[16:32]=v_tgt
    {
        int c = t >> 4, r = t & 15;
        double v = 0.0;
        for (int k = r; k < K1_BLOCKS; k += 16) v += partials[k * 32 + c];
        v += __shfl_xor(v, 1); v += __shfl_xor(v, 2);
        v += __shfl_xor(v, 4); v += __shfl_xor(v, 8);
        if (r == 0) xs[c] = (float)v;
    }
    // stage weights
    for (int i = t; i < 8192; i += 512) w1s[i] = w1g[i];
    if (t < 256) b1s[t] = b1g[t];
    if (t < 128) b2s[t] = b2g[t];

    float w3r[128];                       // column t of w3 (128x512), register-resident
#pragma unroll
    for (int k = 0; k < 128; k++) w3r[k] = w3g[k * 512 + t];
    const float b3r = b3g[t];
    const int j2 = t & 127, p2 = t >> 7;  // 4 threads per h2 output
    float w2r[64];                        // quarter-column of w2 (256x128)
#pragma unroll
    for (int k = 0; k < 64; k++) w2r[k] = w2g[(p2 * 64 + k) * 128 + j2];

    int ns = nsp[0];
    if (ns > 64) ns = 64;
    if (ns < 0)  ns = 0;
    __syncthreads();

    for (int step = 0; step < ns; step++) {
        // ---- layer 1: h1 = relu(x @ w1 + b1), 256 outputs ----
        if (t < 256) {
            float a = b1s[t];
#pragma unroll
            for (int i = 0; i < 32; i++) a = fmaf(xs[i], w1s[i * 256 + t], a);
            h1s[t] = fmaxf(a, 0.0f);
        }
        __syncthreads();
        // ---- layer 2: h2 = relu(h1 @ w2 + b2), 128 outputs, 4-way split ----
        {
            const float4* h1q = (const float4*)(h1s + p2 * 64);
            float a = 0.0f;
#pragma unroll
            for (int kk = 0; kk < 16; kk++) {
                float4 h = h1q[kk];
                a = fmaf(h.x, w2r[4 * kk + 0], a);
                a = fmaf(h.y, w2r[4 * kk + 1], a);
                a = fmaf(h.z, w2r[4 * kk + 2], a);
                a = fmaf(h.w, w2r[4 * kk + 3], a);
            }
            h2p[p2 * 128 + j2] = a;
        }
        __syncthreads();
        if (t < 128) {
            float b = ((h2p[t] + h2p[128 + t]) + (h2p[256 + t] + h2p[384 + t])) + b2s[t];
            h2s[t] = fmaxf(b, 0.0f);
        }
        __syncthreads();
        // ---- layer 3: logits = h2 @ w3 + b3, 512 outputs (one per thread) ----
        float lg = b3r;
        {
            const float4* h2q = (const float4*)h2s;
#pragma unroll
            for (int kk = 0; kk < 32; kk++) {
                float4 h = h2q[kk];
                lg = fmaf(h.x, w3r[4 * kk + 0], lg);
                lg = fmaf(h.y, w3r[4 * kk + 1], lg);
                lg = fmaf(h.z, w3r[4 * kk + 2], lg);
                lg = fmaf(h.w, w3r[4 * kk + 3], lg);
            }
        }
        outL[step * 512 + t] = lg;

        // ---- argmax(logits + gumbel), first-index tie-break ----
        float key = lg + gum[step * 512 + t];
        int   idx = t;
#pragma unroll
        for (int off = 32; off; off >>= 1) {
            float ok = __shfl_down(key, off);
            int   oi = __shfl_down(idx, off);
            if (ok > key || (ok == key && oi < idx)) { key = ok; idx = oi; }
        }
        if ((t & 63) == 0) { rkeys[t >> 6] = key; ridx[t >> 6] = idx; }
        __syncthreads();

        // ---- rotation: v = normalize(expm(omega) @ v), wave 0 only ----
        if (t < 64) {
            float bk = rkeys[0]; int bi = ridx[0];
#pragma unroll
            for (int w = 1; w < 8; w++) {
                float ok = rkeys[w]; int oi = ridx[w];
                if (ok > bk || (ok == bk && oi < bi)) { bk = ok; bi = oi; }
            }
            const float* crow = tc + bi * 120;
            const int i = t & 15, q = t >> 4;   // lane owns row i, column group [4q,4q+4)
            float omr[4];
#pragma unroll
            for (int c = 0; c < 4; c++) {
                int j = 4 * q + c;
                float val = 0.0f;
                if (i < j)      val = -crow[(i * (31 - i)) / 2 + (j - i - 1)];
                else if (i > j) val =  crow[(j * (31 - j)) / 2 + (i - j - 1)];
                omr[c] = val;
            }
            float wv = xs[i];       // current v[i], replicated across q-groups
            float sum = wv;         // k=0 term
#pragma unroll
            for (int k = 1; k <= 20; k++) {
                float w0 = __shfl(wv, 20 * q + 0);
                float w1v = __shfl(wv, 20 * q + 1);
                float w2v = __shfl(wv, 20 * q + 2);
                float w3v = __shfl(wv, 20 * q + 3);
                float pr = omr[0] * w0;
                pr = fmaf(omr[1], w1v, pr);
                pr = fmaf(omr[2], w2v, pr);
                pr = fmaf(omr[3], w3v, pr);
                pr += __shfl_xor(pr, 16);
                pr += __shfl_xor(pr, 32);
                wv = pr * (1.0f / (float)k);
                sum += wv;
            }
            float n2 = sum * sum;
            n2 += __shfl_xor(n2, 1);
            n2 += __shfl_xor(n2, 2);
            n2 += __shfl_xor(n2, 4);
            n2 += __shfl_xor(n2, 8);
            float invn = 1.0f / sqrtf(n2);
            float vn = sum * invn;
            if (t < 16) {
                xs[t] = vn;
                if (step == ns - 1) vf_out[t] = vn;
            }
        }
        __syncthreads();
    }
}

// -------------------- K3: scores = exp(dot(v_fin, emb_row_normalized)), block sums --------------------
extern "C" __global__ __launch_bounds__(256)
void k_scores(const float* __restrict__ emb, const float* __restrict__ vf16,
              float* __restrict__ outP, double* __restrict__ sums)
{
    __shared__ float vfs[16];
    const int tid = threadIdx.x;
    const int bid = blockIdx.x;
    if (tid < 16) vfs[tid] = vf16[tid];
    __syncthreads();
    float v[16];
#pragma unroll
    for (int i = 0; i < 16; i++) v[i] = vfs[i];

    double bsum = 0.0;
    for (long long r = (long long)bid * 256 + tid; r < M_TOTAL; r += (long long)K1_BLOCKS * 256) {
        const float4* ep = (const float4*)(emb + r * 16);
        float4 e0 = ep[0], e1 = ep[1], e2 = ep[2], e3 = ep[3];
        float ev[16] = { e0.x,e0.y,e0.z,e0.w, e1.x,e1.y,e1.z,e1.w,
                         e2.x,e2.y,e2.z,e2.w, e3.x,e3.y,e3.z,e3.w };
        float n2 = 0.0f;
#pragma unroll
        for (int i = 0; i < 16; i++) n2 = fmaf(ev[i], ev[i], n2);
        float invn = 1.0f / sqrtf(n2);
        float dot = 0.0f;
#pragma unroll
        for (int i = 0; i < 16; i++) dot = fmaf(ev[i], v[i], dot);
        float e = expf(dot * invn);   // |score| <= 1, no overflow; softmax shift cancels
        outP[r] = e;
        bsum += (double)e;
    }
    // wave + block reduce
#pragma unroll
    for (int off = 32; off; off >>= 1) bsum += __shfl_down(bsum, off);
    __shared__ double lred[4];
    if ((tid & 63) == 0) lred[tid >> 6] = bsum;
    __syncthreads();
    if (tid == 0) sums[bid] = lred[0] + lred[1] + lred[2] + lred[3];
}

// -------------------- K4: total and reciprocal --------------------
extern "C" __global__ __launch_bounds__(256)
void k_total(const double* __restrict__ sums, double* __restrict__ invp)
{
    const int tid = threadIdx.x;
    double v = 0.0;
    for (int k = tid; k < K1_BLOCKS; k += 256) v += sums[k];
#pragma unroll
    for (int off = 32; off; off >>= 1) v += __shfl_down(v, off);
    __shared__ double lred[4];
    if ((tid & 63) == 0) lred[tid >> 6] = v;
    __syncthreads();
    if (tid == 0) invp[0] = 1.0 / (lred[0] + lred[1] + lred[2] + lred[3]);
}

// -------------------- K5: normalize --------------------
extern "C" __global__ __launch_bounds__(256)
void k_scale(float* __restrict__ outP, const double* __restrict__ invp)
{
    const float inv = (float)invp[0];
    long long r4 = (long long)blockIdx.x * 256 + threadIdx.x;
    if (r4 < M_TOTAL / 4) {
        float4* p = (float4*)outP;
        float4 v = p[r4];
        v.x *= inv; v.y *= inv; v.z *= inv; v.w *= inv;
        p[r4] = v;
    }
}

extern "C" void kernel_launch(void* const* d_in, const int* in_sizes, int n_in,
                              void* d_out, int out_size, void* d_ws, size_t ws_size,
                              hipStream_t stream)
{
    const float* vsrc = (const float*)d_in[0];
    const float* vtgt = (const float*)d_in[1];
    const float* emb  = (const float*)d_in[2];
    const float* tc   = (const float*)d_in[3];
    // d_in[4] = bases: structure is hard-coded (omega[i][j] = -/+ coeffs[t*, k(i,j)])
    const float* w1 = (const float*)d_in[5];
    const float* b1 = (const float*)d_in[6];
    const float* w2 = (const float*)d_in[7];
    const float* b2 = (const float*)d_in[8];
    const float* w3 = (const float*)d_in[9];
    const float* b3 = (const float*)d_in[10];
    const float* gum = (const float*)d_in[11];
    const int* nsp   = (const int*)d_in[12];

    float* outP = (float*)d_out;          // pred_marking [2M]
    float* outL = outP + M_TOTAL;         // logits [64*512]

    double* wsd      = (double*)d_ws;
    double* partials = wsd;                         // 2048*32 doubles
    double* sums     = wsd + K1_BLOCKS * 32;        // 2048 doubles
    double* invp     = sums + K1_BLOCKS;            // 1 double
    float*  vf       = (float*)(invp + 1);          // 16 floats

    k_reduce<<<K1_BLOCKS, 256, 0, stream>>>(emb, vsrc, vtgt, partials);
    k_steps<<<1, 512, 0, stream>>>(partials, w1, b1, w2, b2, w3, b3, tc, gum, nsp, outL, vf);
    k_scores<<<K1_BLOCKS, 256, 0, stream>>>(emb, vf, outP, sums);
    k_total<<<1, 256, 0, stream>>>(sums, invp);
    k_scale<<<(M_TOTAL / 4 + 255) / 256, 256, 0, stream>>>(outP, invp);
}